// Round 11
// baseline (491.487 us; speedup 1.0000x reference)
//
#include <hip/hip_runtime.h>

typedef short short8 __attribute__((ext_vector_type(8)));
typedef unsigned short us4 __attribute__((ext_vector_type(4)));
typedef float floatx4 __attribute__((ext_vector_type(4)));
typedef unsigned short u16;

#define NN 16384
#define NE 131072
#define NEF_ 128
#define DD 56
#define INV_SQRT3F 0.57735026918962576f
#define PATH_NORMF 0.15811388300841897f

__device__ __forceinline__ float bf2f(u16 u) {
    union { unsigned int i; float f; } v; v.i = ((unsigned int)u) << 16; return v.f;
}
__device__ __forceinline__ u16 f2bf(float f) {
    union { float f; unsigned int i; } v; v.f = f;
    unsigned int r = v.i + 0x7fffu + ((v.i >> 16) & 1u);
    return (u16)(r >> 16);
}

// ---------------- K0: transpose W1/W2 + edge-src histogram (merged) ----------------
__global__ __launch_bounds__(256) void prep(const float* __restrict__ W1,
                                            const float* __restrict__ W2,
                                            u16* __restrict__ W1T,
                                            u16* __restrict__ W2T,
                                            const int* __restrict__ eidx,
                                            int* __restrict__ deg) {
    int b = blockIdx.x;
    if (b < 864) {
        int i = b * 256 + threadIdx.x;
        if (i < 16384) {
            int n = i >> 7, k = i & 127;
            W1T[i] = f2bf(W1[k * 128 + n]);
        } else {
            int j = i - 16384;
            int n = j >> 7, k = j & 127;
            W2T[j] = f2bf(W2[k * 1600 + n]);
        }
    } else {
        int e = (b - 864) * 256 + threadIdx.x;
        atomicAdd(&deg[eidx[e]], 1);
    }
}

__global__ __launch_bounds__(1024) void deg_scan(const int* __restrict__ deg,
                                                 int* __restrict__ row_start,
                                                 int* __restrict__ cursor) {
    __shared__ int part[1024];
    const int t = threadIdx.x;
    const int base = t * 16;
    int loc[16];
    int s = 0;
    #pragma unroll
    for (int i = 0; i < 16; i++) { loc[i] = s; s += deg[base + i]; }
    part[t] = s;
    __syncthreads();
    for (int off = 1; off < 1024; off <<= 1) {
        int v = (t >= off) ? part[t - off] : 0;
        __syncthreads();
        part[t] += v;
        __syncthreads();
    }
    int pre = (t == 0) ? 0 : part[t - 1];
    #pragma unroll
    for (int i = 0; i < 16; i++) {
        int v = pre + loc[i];
        row_start[base + i] = v;
        cursor[base + i] = v;
    }
    if (t == 1023) row_start[16384] = pre + s;
}

__global__ __launch_bounds__(256) void edge_scatter(const int* __restrict__ eidx,
                                                    int* __restrict__ cursor,
                                                    int* __restrict__ edge_order) {
    int e = blockIdx.x * 256 + threadIdx.x;
    int p = atomicAdd(&cursor[eidx[e]], 1);
    edge_order[p] = e;
}

// chunk GEMM helpers (named buffers -> static register allocation, no spills)
#define CHUNK_MFMA(FA, C)                                                        \
    floatx4 acc[2];                                                              \
    {                                                                            \
        floatx4 bias = *(const floatx4*)&b2s[(C) * 64 + cg * 16 + q * 4];        \
        acc[0] = bias; acc[1] = bias;                                            \
        _Pragma("unroll")                                                        \
        for (int kk = 0; kk < 4; kk++) {                                         \
            acc[0] = __builtin_amdgcn_mfma_f32_16x16x32_bf16(FA[kk], hc[0][kk], acc[0], 0, 0, 0); \
            acc[1] = __builtin_amdgcn_mfma_f32_16x16x32_bf16(FA[kk], hc[1][kk], acc[1], 0, 0, 0); \
        }                                                                        \
    }

#define PREFETCH_G(FA, C)                                                        \
    _Pragma("unroll")                                                            \
    for (int kk = 0; kk < 4; kk++)                                               \
        FA[kk] = *(const short8*)(wfrag + (size_t)(C) * 8192 + kk * 32);

#define CONSUME_SS(C)                                                            \
    {                                                                            \
        const int i = 2 * (C) + (cg >> 1);                                       \
        _Pragma("unroll")                                                        \
        for (int et = 0; et < 2; et++) {                                         \
            float f = bf2f(sF[i * 64 + eb + et * 16 + m]) * ssc[et];             \
            _Pragma("unroll")                                                    \
            for (int r = 0; r < 4; r++) tps[et][r] += acc[et][r] * f;            \
        }                                                                        \
    }

#define CONSUME_VS(C)                                                            \
    {                                                                            \
        const int i = 2 * ((C) - 16) + (cg >> 1);                                \
        _Pragma("unroll")                                                        \
        for (int et = 0; et < 2; et++) {                                         \
            float f = bf2f(sF[(32 + i) * 64 + eb + et * 16 + m]);                \
            _Pragma("unroll")                                                    \
            for (int r = 0; r < 4; r++) tps[et][r] += acc[et][r] * f;            \
        }                                                                        \
    }

#define CONSUME_SV(C)                                                            \
    {                                                                            \
        const int i = 8 * ((C) - 20) + cg * 2 + (q >> 1);                        \
        _Pragma("unroll")                                                        \
        for (int et = 0; et < 2; et++) {                                         \
            float f = bf2f(sF[i * 64 + eb + et * 16 + m]);                       \
            _Pragma("unroll")                                                    \
            for (int r = 0; r < 4; r++) {                                        \
                float t0 = acc[et][r] * f;                                       \
                tpv[et][r][0] += t0 * svc[et][0];                                \
                tpv[et][r][1] += t0 * svc[et][1];                                \
                tpv[et][r][2] += t0 * svc[et][2];                                \
            }                                                                    \
        }                                                                        \
    }

// ---------------- K2: fused MLP + tensor product, 512 threads, barrier-free chunk loop ----------------
// 8 waves: cg = wv&3 (16 w-cols), eh = wv>>2 (32 edges, 2 et-tiles).
// Chunk GEMM: A = per-lane GLOBAL W2T fragments (L1/L2-hot), B = h in regs, consume from acc.
__global__ __launch_bounds__(512, 4) void tpconv(
    const float* __restrict__ node_attr, const float* __restrict__ edge_attr,
    const float* __restrict__ edge_sh, const u16* __restrict__ W1T,
    const float* __restrict__ b1, const u16* __restrict__ W2T,
    const float* __restrict__ b2, const int* __restrict__ eidx,
    const int* __restrict__ edge_order,
    float* __restrict__ tp)
{
    __shared__ __align__(16) char smem[49920];
    u16*   sA  = (u16*)smem;                 // 64*136 u16 = 17408 B (edge_attr, then h)
    u16*   sB  = (u16*)(smem + 17408);       // 17408 B (W1T for h-phase only)
    u16*   sF  = (u16*)(smem + 34816);       // 68*64 u16 = 8704 B (factors [row][edge])
    float* b2s = (float*)(smem + 43520);     // 1600 f32 = 6400 B -> 49920
    float* Ssc  = (float*)smem;              // overlay: 2 * 64*33 f32 = 16896 B
    float* Svec = (float*)(smem + 16896);    // overlay: 4 * 64*25 f32 -> 42496

    const int t = threadIdx.x;
    const int lane = t & 63;
    const int wv = t >> 6;           // 0..7
    const int m = lane & 15;
    const int q = lane >> 4;
    const int cg = wv & 3;           // col-group (16 w-cols)
    const int eh = wv >> 2;          // edge-half
    const int eb = eh * 32;          // edge base
    const int p0 = blockIdx.x * 64;  // CSR position base
    const int str = t >> 4;          // 0..31
    const int stc = (t & 15) * 8;

    // per-lane A-fragment base in W2T; double-buffered named frags
    const u16* wfrag = W2T + (size_t)(cg * 16 + m) * 128 + q * 8;
    short8 fa0[4], fa1[4];
    PREFETCH_G(fa0, 0)
    PREFETCH_G(fa1, 1)

    for (int i = t; i < 1600; i += 512) b2s[i] = b2[i];

    // stage edge_attr tile (64 gathered rows, fp32 -> bf16)
    #pragma unroll
    for (int ii = 0; ii < 4; ii++) {
        int cid = t + 512 * ii;
        int r = cid >> 5, s = cid & 31;
        int e = edge_order[p0 + r];
        const float* src = &edge_attr[(size_t)e * NEF_ + s * 4];
        us4 o;
        o.x = f2bf(src[0]); o.y = f2bf(src[1]); o.z = f2bf(src[2]); o.w = f2bf(src[3]);
        *(us4*)&sA[r * 136 + s * 4] = o;
    }
    // per-edge factors (wave 0)
    if (t < 64) {
        int e = edge_order[p0 + t];
        int nd = eidx[NE + e];
        const float* na = node_attr + (size_t)nd * DD;
        const float* sh = edge_sh + (size_t)e * 4;
        float ss = sh[0], s0 = sh[1], s1 = sh[2], s2 = sh[3];
        #pragma unroll
        for (int i = 0; i < 32; i++) sF[i * 64 + t] = f2bf(na[i]);
        #pragma unroll
        for (int i = 0; i < 8; i++) {
            float d = (na[32+i*3]*s0 + na[33+i*3]*s1 + na[34+i*3]*s2) * INV_SQRT3F;
            sF[(32 + i) * 64 + t] = f2bf(d);
        }
        #pragma unroll
        for (int i = 0; i < 24; i++) sF[(40 + i) * 64 + t] = f2bf(na[32 + i]);
        sF[64 * 64 + t] = f2bf(ss);
        sF[65 * 64 + t] = f2bf(s0);
        sF[66 * 64 + t] = f2bf(s1);
        sF[67 * 64 + t] = f2bf(s2);
    }
    __syncthreads();

    // ---- h = relu(ea @ W1 + b1), two 64-col passes ----
    floatx4 hacc[2][2];
    #pragma unroll
    for (int cc = 0; cc < 2; cc++) {
        #pragma unroll
        for (int ii = 0; ii < 2; ii++)
            *(short8*)&sB[(str + 32 * ii) * 136 + stc] =
                *(const short8*)&W1T[(size_t)(cc * 64 + str + 32 * ii) * 128 + stc];
        __syncthreads();
        {
            float bv = b1[cc * 64 + cg * 16 + m];
            hacc[cc][0] = (floatx4){bv, bv, bv, bv};
            hacc[cc][1] = hacc[cc][0];
        }
        #pragma unroll
        for (int k0 = 0; k0 < 128; k0 += 32) {
            short8 a0 = *(const short8*)&sA[(eb      + m) * 136 + k0 + q * 8];
            short8 a1 = *(const short8*)&sA[(eb + 16 + m) * 136 + k0 + q * 8];
            short8 bA = *(const short8*)&sB[(cg * 16 + m) * 136 + k0 + q * 8];
            hacc[cc][0] = __builtin_amdgcn_mfma_f32_16x16x32_bf16(a0, bA, hacc[cc][0], 0, 0, 0);
            hacc[cc][1] = __builtin_amdgcn_mfma_f32_16x16x32_bf16(a1, bA, hacc[cc][1], 0, 0, 0);
        }
        __syncthreads();
    }
    // write h (relu, bf16): row(edge) = eb + rt*16 + q*4+r, col = cc*64 + cg*16 + m
    #pragma unroll
    for (int cc = 0; cc < 2; cc++)
      #pragma unroll
      for (int rt = 0; rt < 2; rt++)
        #pragma unroll
        for (int r = 0; r < 4; r++) {
            int e   = eb + rt * 16 + q * 4 + r;
            int col = cc * 64 + cg * 16 + m;
            float v = hacc[cc][rt][r];
            sA[e * 136 + col] = f2bf(v > 0.f ? v : 0.f);
        }
    __syncthreads();   // h complete — last barrier before the post-loop one

    // h-cache: B-fragments for this wave's 2 edge-tiles (32 VGPR, reused 25x)
    short8 hc[2][4];
    #pragma unroll
    for (int et = 0; et < 2; et++)
        #pragma unroll
        for (int kk = 0; kk < 4; kk++)
            hc[et][kk] = *(const short8*)&sA[(eb + et * 16 + m) * 136 + kk * 32 + q * 8];

    float ssc[2], svc[2][3];
    #pragma unroll
    for (int et = 0; et < 2; et++) {
        ssc[et] = bf2f(sF[64 * 64 + eb + et * 16 + m]);
        svc[et][0] = bf2f(sF[65 * 64 + eb + et * 16 + m]);
        svc[et][1] = bf2f(sF[66 * 64 + eb + et * 16 + m]);
        svc[et][2] = bf2f(sF[67 * 64 + eb + et * 16 + m]);
    }

    float tps[2][4];     // [et][r]: out_s[e=eb+et*16+m][j=(cg&1)*16+q*4+r], half=(cg>>1)
    float tpv[2][4][3];  // [et][r][mm]: out_v[e][jv=(q&1)*4+r][mm], slot=cg, parity=(q>>1)
    #pragma unroll
    for (int et = 0; et < 2; et++)
        #pragma unroll
        for (int r = 0; r < 4; r++) {
            tps[et][r] = 0.f;
            tpv[et][r][0] = 0.f; tpv[et][r][1] = 0.f; tpv[et][r][2] = 0.f;
        }

    // ---- 25 chunks: global A-frags, register h, register consume — NO barriers ----
    #pragma unroll 1
    for (int c = 0; c < 16; c += 2) {
        { CHUNK_MFMA(fa0, c)     PREFETCH_G(fa0, c + 2) CONSUME_SS(c) }
        { CHUNK_MFMA(fa1, c + 1) PREFETCH_G(fa1, c + 3) CONSUME_SS(c + 1) }
    }
    #pragma unroll 1
    for (int c = 16; c < 20; c += 2) {
        { CHUNK_MFMA(fa0, c)     PREFETCH_G(fa0, c + 2) CONSUME_VS(c) }
        { CHUNK_MFMA(fa1, c + 1) PREFETCH_G(fa1, c + 3) CONSUME_VS(c + 1) }
    }
    #pragma unroll 1
    for (int c = 20; c < 24; c += 2) {
        { CHUNK_MFMA(fa0, c)     PREFETCH_G(fa0, c + 2) CONSUME_SV(c) }
        {
            CHUNK_MFMA(fa1, c + 1)
            if (c + 3 < 25) { PREFETCH_G(fa1, c + 3) }
            CONSUME_SV(c + 1)
        }
    }
    {   // chunk 24 (vv)
        CHUNK_MFMA(fa0, 24)
        const int i = cg * 2 + (q >> 1);
        #pragma unroll
        for (int et = 0; et < 2; et++) {
            float x0 = bf2f(sF[(40 + 3 * i + 0) * 64 + eb + et * 16 + m]) * ssc[et];
            float x1 = bf2f(sF[(40 + 3 * i + 1) * 64 + eb + et * 16 + m]) * ssc[et];
            float x2 = bf2f(sF[(40 + 3 * i + 2) * 64 + eb + et * 16 + m]) * ssc[et];
            #pragma unroll
            for (int r = 0; r < 4; r++) {
                tpv[et][r][0] += acc[et][r] * x0;
                tpv[et][r][1] += acc[et][r] * x1;
                tpv[et][r][2] += acc[et][r] * x2;
            }
        }
    }
    __syncthreads();   // all sF/b2s reads drained before overlay writes

    // ---- end-stage combine (overlay smem) ----
    #pragma unroll
    for (int et = 0; et < 2; et++)
        #pragma unroll
        for (int r = 0; r < 4; r++)
            Ssc[(cg >> 1) * 2112 + (eb + et * 16 + m) * 33 + (cg & 1) * 16 + q * 4 + r] = tps[et][r];
    #pragma unroll
    for (int et = 0; et < 2; et++)
        #pragma unroll
        for (int r = 0; r < 4; r++)
            #pragma unroll
            for (int mm = 0; mm < 3; mm++) {
                float v = tpv[et][r][mm];
                v += __shfl_xor(v, 32, 64);
                if (q < 2)
                    Svec[cg * 1600 + (eb + et * 16 + m) * 25 + ((q & 1) * 4 + r) * 3 + mm] = v;
            }
    __syncthreads();

    for (int idx = t; idx < 3584; idx += 512) {
        int e = idx / 56, d = idx - e * 56;
        float v;
        if (d < 32) {
            v = Ssc[e * 33 + d] + Ssc[2112 + e * 33 + d];
        } else {
            int dd = d - 32;
            v = Svec[e * 25 + dd] + Svec[1600 + e * 25 + dd]
              + Svec[3200 + e * 25 + dd] + Svec[4800 + e * 25 + dd];
        }
        tp[(size_t)(p0 + e) * DD + d] = v * PATH_NORMF;   // CSR position order
    }
}

// ---------------- K3: contiguous segment-mean + residual + BN stat atomics ----------------
__global__ __launch_bounds__(256) void gather_finalize(
    const float* __restrict__ tp, const int* __restrict__ row_start,
    const float* __restrict__ node_attr,
    float* __restrict__ ybuf, float* __restrict__ stats)
{
    __shared__ float ps[4][72];
    const int wv = threadIdx.x >> 6, lane = threadIdx.x & 63;
    const int n = blockIdx.x * 4 + wv;    // 4096 blocks
    const int beg = row_start[n], end = row_start[n + 1];
    if (lane < 56) {
        float acc = 0.f;
        for (int p = beg; p < end; p++)
            acc += tp[(size_t)p * DD + lane];   // fully coalesced, sequential
        float inv = 1.f / fmaxf((float)(end - beg), 1.f);
        float y = acc * inv + node_attr[(size_t)n * DD + lane];
        ybuf[(size_t)n * DD + lane] = y;
        if (lane < 32) {
            ps[wv][lane] = y;
            ps[wv][32 + lane] = y * y;
        } else {
            float vv = y * y;
            float v1 = __shfl_down(vv, 1, 64);
            float v2 = __shfl_down(vv, 2, 64);
            int l3 = lane - 32;
            if (l3 % 3 == 0) ps[wv][64 + l3 / 3] = vv + v1 + v2;
        }
    }
    __syncthreads();
    const int t = threadIdx.x;
    if (t < 72)
        atomicAdd(&stats[t], ps[0][t] + ps[1][t] + ps[2][t] + ps[3][t]);
}

// ---------------- K4: batch-norm apply + write fp32 output ----------------
__global__ __launch_bounds__(256) void bn_apply(
    const float* __restrict__ ybuf, const float* __restrict__ stats,
    const float* __restrict__ gamma, const float* __restrict__ beta,
    float* __restrict__ out)
{
    const int i = blockIdx.x * 256 + threadIdx.x;   // 3584*256 = 917504
    const int n = i / 56;
    const int d = i - n * 56;
    const float invN = 1.f / 16384.f;
    float y = ybuf[i];
    float o;
    if (d < 32) {
        float mn  = stats[d] * invN;
        float var = stats[32 + d] * invN - mn * mn;
        o = (y - mn) * rsqrtf(var + 1e-5f) * gamma[d] + beta[d];
    } else {
        int jv = (d - 32) / 3;
        o = y * rsqrtf(stats[64 + jv] * invN + 1e-5f) * gamma[32 + jv];
    }
    out[i] = o;
}

// ---------------- launch ----------------
extern "C" void kernel_launch(void* const* d_in, const int* in_sizes, int n_in,
                              void* d_out, int out_size, void* d_ws, size_t ws_size,
                              hipStream_t stream)
{
    const float* node_attr = (const float*)d_in[0];
    const float* edge_attr = (const float*)d_in[1];
    const float* edge_sh   = (const float*)d_in[2];
    const float* W1        = (const float*)d_in[3];
    const float* b1        = (const float*)d_in[4];
    const float* W2        = (const float*)d_in[5];
    const float* b2        = (const float*)d_in[6];
    const float* gamma     = (const float*)d_in[7];
    const float* beta      = (const float*)d_in[8];
    const int*   eidx      = (const int*)d_in[9];

    char* ws = (char*)d_ws;
    u16*   W1T        = (u16*)(ws);                  // 32768 B
    u16*   W2T        = (u16*)(ws + 32768);          // 409600   -> 442368
    int*   deg        = (int*)(ws + 442368);         // 65536    -> 507904
    float* stats      = (float*)(ws + 507904);       // 512      -> 508416   (memset w/ deg)
    int*   row_start  = (int*)(ws + 508416);         // 65792    -> 574208
    int*   cursor     = (int*)(ws + 574208);         // 65536    -> 639744
    int*   edge_order = (int*)(ws + 639744);         // 524288   -> 1164032
    float* tp         = (float*)(ws + 1164032);      // 29360128 -> 30524160
    float* ybuf       = (float*)(ws + 30524160);     // 3670016  -> 34194176 (~34.2 MB)

    (void)hipMemsetAsync(deg, 0, 66048, stream);     // deg + stats
    hipLaunchKernelGGL(prep,            dim3(1376), dim3(256),  0, stream,
                       W1, W2, W1T, W2T, eidx, deg);
    hipLaunchKernelGGL(deg_scan,        dim3(1),    dim3(1024), 0, stream, deg, row_start, cursor);
    hipLaunchKernelGGL(edge_scatter,    dim3(512),  dim3(256),  0, stream, eidx, cursor, edge_order);
    hipLaunchKernelGGL(tpconv,          dim3(2048), dim3(512),  0, stream,
                       node_attr, edge_attr, edge_sh, W1T, b1, W2T, b2, eidx, edge_order, tp);
    hipLaunchKernelGGL(gather_finalize, dim3(4096), dim3(256),  0, stream,
                       tp, row_start, node_attr, ybuf, stats);
    hipLaunchKernelGGL(bn_apply,        dim3(3584), dim3(256),  0, stream,
                       ybuf, stats, gamma, beta, (float*)d_out);
}

// Round 12
// 334.334 us; speedup vs baseline: 1.4700x; 1.4700x over previous
//
#include <hip/hip_runtime.h>

typedef short short8 __attribute__((ext_vector_type(8)));
typedef unsigned short us4 __attribute__((ext_vector_type(4)));
typedef float floatx4 __attribute__((ext_vector_type(4)));
typedef unsigned short u16;

#define NN 16384
#define NE 131072
#define NEF_ 128
#define DD 56
#define INV_SQRT3F 0.57735026918962576f
#define PATH_NORMF 0.15811388300841897f

__device__ __forceinline__ float bf2f(u16 u) {
    union { unsigned int i; float f; } v; v.i = ((unsigned int)u) << 16; return v.f;
}
__device__ __forceinline__ u16 f2bf(float f) {
    union { float f; unsigned int i; } v; v.f = f;
    unsigned int r = v.i + 0x7fffu + ((v.i >> 16) & 1u);
    return (u16)(r >> 16);
}

// ---------------- K0: build FRAG-MAJOR W1f/W2f + edge-src histogram ----------------
// W1f: cc*8192 + kk*2048 + cg*512 + lane*8 + j  <- W1[(kk*32+q*8+j)*128 + cc*64+cg*16+m]
// W2f: c*8192  + kk*2048 + cg*512 + lane*8 + j  <- W2[(kk*32+q*8+j)*1600 + c*64+cg*16+m]
__global__ __launch_bounds__(256) void prep(const float* __restrict__ W1,
                                            const float* __restrict__ W2,
                                            u16* __restrict__ W1f,
                                            u16* __restrict__ W2f,
                                            const int* __restrict__ eidx,
                                            int* __restrict__ deg) {
    int b = blockIdx.x;
    if (b < 864) {
        int i = b * 256 + threadIdx.x;   // 221184 = 16384 + 204800
        if (i < 16384) {
            int cc = i >> 13, kk = (i >> 11) & 3, cg = (i >> 9) & 3;
            int lane = (i >> 3) & 63, j = i & 7;
            int q = lane >> 4, m = lane & 15;
            W1f[i] = f2bf(W1[(kk * 32 + q * 8 + j) * 128 + cc * 64 + cg * 16 + m]);
        } else {
            int f = i - 16384;
            int c = f >> 13, kk = (f >> 11) & 3, cg = (f >> 9) & 3;
            int lane = (f >> 3) & 63, j = f & 7;
            int q = lane >> 4, m = lane & 15;
            W2f[f] = f2bf(W2[(kk * 32 + q * 8 + j) * 1600 + c * 64 + cg * 16 + m]);
        }
    } else {
        int e = (b - 864) * 256 + threadIdx.x;
        atomicAdd(&deg[eidx[e]], 1);
    }
}

__global__ __launch_bounds__(1024) void deg_scan(const int* __restrict__ deg,
                                                 int* __restrict__ row_start,
                                                 int* __restrict__ cursor) {
    __shared__ int part[1024];
    const int t = threadIdx.x;
    const int base = t * 16;
    int loc[16];
    int s = 0;
    #pragma unroll
    for (int i = 0; i < 16; i++) { loc[i] = s; s += deg[base + i]; }
    part[t] = s;
    __syncthreads();
    for (int off = 1; off < 1024; off <<= 1) {
        int v = (t >= off) ? part[t - off] : 0;
        __syncthreads();
        part[t] += v;
        __syncthreads();
    }
    int pre = (t == 0) ? 0 : part[t - 1];
    #pragma unroll
    for (int i = 0; i < 16; i++) {
        int v = pre + loc[i];
        row_start[base + i] = v;
        cursor[base + i] = v;
    }
    if (t == 1023) row_start[16384] = pre + s;
}

__global__ __launch_bounds__(256) void edge_scatter(const int* __restrict__ eidx,
                                                    int* __restrict__ cursor,
                                                    int* __restrict__ edge_order) {
    int e = blockIdx.x * 256 + threadIdx.x;
    int p = atomicAdd(&cursor[eidx[e]], 1);
    edge_order[p] = e;
}

// ---------------- K2: fused MLP + tensor product, 512 threads, frag-major LDS ----------------
// 8 waves: cg = wv&3 (16 w-cols), eh = wv>>2 (32 edges, 2 et-tiles).
// Chunk GEMM: A = W2f chunk (conflict-free frag-major LDS), B = h in regs, consume from acc.
__global__ __launch_bounds__(512, 4) void tpconv(
    const float* __restrict__ node_attr, const float* __restrict__ edge_attr,
    const float* __restrict__ edge_sh, const u16* __restrict__ W1f,
    const float* __restrict__ b1, const u16* __restrict__ W2f,
    const float* __restrict__ b2, const int* __restrict__ eidx,
    const int* __restrict__ edge_order,
    float* __restrict__ tp)
{
    __shared__ __align__(16) char smem[48896];
    u16*   sA  = (u16*)smem;                 // 64*136 u16 = 17408 B (edge_attr, then h)
    u16*   B2  = (u16*)(smem + 17408);       // 8192 u16 = 16384 B frag-major chunk -> 33792
    u16*   sF  = (u16*)(smem + 33792);       // 68*64 u16 = 8704 B -> 42496
    float* b2s = (float*)(smem + 42496);     // 1600 f32 = 6400 B -> 48896
    float* Ssc  = (float*)smem;              // overlay: 2 * 64*33 f32 = 16896 B
    float* Svec = (float*)(smem + 16896);    // overlay: 4 * 64*25 f32 -> 42496 (b2s untouched)

    const int t = threadIdx.x;
    const int lane = t & 63;
    const int wv = t >> 6;           // 0..7
    const int m = lane & 15;
    const int q = lane >> 4;
    const int cg = wv & 3;           // col-group (16 w-cols)
    const int eh = wv >> 2;          // edge-half
    const int eb = eh * 32;          // edge base
    const int p0 = blockIdx.x * 64;  // CSR position base

    // early prefetch of W2f chunk 0 (contiguous: 2 x 16B per thread)
    short8 pre[2];
    #pragma unroll
    for (int ii = 0; ii < 2; ii++)
        pre[ii] = *(const short8*)&W2f[ii * 4096 + t * 8];

    for (int i = t; i < 1600; i += 512) b2s[i] = b2[i];

    // stage edge_attr tile (64 gathered rows, fp32 -> bf16)
    #pragma unroll
    for (int ii = 0; ii < 4; ii++) {
        int cid = t + 512 * ii;
        int r = cid >> 5, s = cid & 31;
        int e = edge_order[p0 + r];
        const float* src = &edge_attr[(size_t)e * NEF_ + s * 4];
        us4 o;
        o.x = f2bf(src[0]); o.y = f2bf(src[1]); o.z = f2bf(src[2]); o.w = f2bf(src[3]);
        *(us4*)&sA[r * 136 + s * 4] = o;
    }
    // per-edge factors (wave 0)
    if (t < 64) {
        int e = edge_order[p0 + t];
        int nd = eidx[NE + e];
        const float* na = node_attr + (size_t)nd * DD;
        const float* sh = edge_sh + (size_t)e * 4;
        float ss = sh[0], s0 = sh[1], s1 = sh[2], s2 = sh[3];
        #pragma unroll
        for (int i = 0; i < 32; i++) sF[i * 64 + t] = f2bf(na[i]);
        #pragma unroll
        for (int i = 0; i < 8; i++) {
            float d = (na[32+i*3]*s0 + na[33+i*3]*s1 + na[34+i*3]*s2) * INV_SQRT3F;
            sF[(32 + i) * 64 + t] = f2bf(d);
        }
        #pragma unroll
        for (int i = 0; i < 24; i++) sF[(40 + i) * 64 + t] = f2bf(na[32 + i]);
        sF[64 * 64 + t] = f2bf(ss);
        sF[65 * 64 + t] = f2bf(s0);
        sF[66 * 64 + t] = f2bf(s1);
        sF[67 * 64 + t] = f2bf(s2);
    }
    __syncthreads();

    // ---- h = relu(ea @ W1 + b1), two 64-col passes; W1f staged frag-major ----
    floatx4 hacc[2][2];
    #pragma unroll
    for (int cc = 0; cc < 2; cc++) {
        #pragma unroll
        for (int ii = 0; ii < 2; ii++)
            *(short8*)&B2[ii * 4096 + t * 8] =
                *(const short8*)&W1f[cc * 8192 + ii * 4096 + t * 8];
        __syncthreads();
        {
            float bv = b1[cc * 64 + cg * 16 + m];
            hacc[cc][0] = (floatx4){bv, bv, bv, bv};
            hacc[cc][1] = hacc[cc][0];
        }
        #pragma unroll
        for (int kk = 0; kk < 4; kk++) {
            short8 a0 = *(const short8*)&sA[(eb      + m) * 136 + kk * 32 + q * 8];
            short8 a1 = *(const short8*)&sA[(eb + 16 + m) * 136 + kk * 32 + q * 8];
            short8 bA = *(const short8*)&B2[(kk * 4 + cg) * 512 + lane * 8];
            hacc[cc][0] = __builtin_amdgcn_mfma_f32_16x16x32_bf16(a0, bA, hacc[cc][0], 0, 0, 0);
            hacc[cc][1] = __builtin_amdgcn_mfma_f32_16x16x32_bf16(a1, bA, hacc[cc][1], 0, 0, 0);
        }
        __syncthreads();
    }
    // write h (relu, bf16): row(edge) = eb + rt*16 + q*4+r, col = cc*64 + cg*16 + m
    #pragma unroll
    for (int cc = 0; cc < 2; cc++)
      #pragma unroll
      for (int rt = 0; rt < 2; rt++)
        #pragma unroll
        for (int r = 0; r < 4; r++) {
            int e   = eb + rt * 16 + q * 4 + r;
            int col = cc * 64 + cg * 16 + m;
            float v = hacc[cc][rt][r];
            sA[e * 136 + col] = f2bf(v > 0.f ? v : 0.f);
        }
    __syncthreads();   // h complete

    // h-cache: B-fragments for this wave's 2 edge-tiles (32 VGPR, reused 25x)
    short8 hc[2][4];
    #pragma unroll
    for (int et = 0; et < 2; et++)
        #pragma unroll
        for (int kk = 0; kk < 4; kk++)
            hc[et][kk] = *(const short8*)&sA[(eb + et * 16 + m) * 136 + kk * 32 + q * 8];

    float ssc[2], svc[2][3];
    #pragma unroll
    for (int et = 0; et < 2; et++) {
        ssc[et] = bf2f(sF[64 * 64 + eb + et * 16 + m]);
        svc[et][0] = bf2f(sF[65 * 64 + eb + et * 16 + m]);
        svc[et][1] = bf2f(sF[66 * 64 + eb + et * 16 + m]);
        svc[et][2] = bf2f(sF[67 * 64 + eb + et * 16 + m]);
    }

    // commit W2f chunk 0 (contiguous, conflict-free); prefetch chunk 1
    #pragma unroll
    for (int ii = 0; ii < 2; ii++)
        *(short8*)&B2[ii * 4096 + t * 8] = pre[ii];
    #pragma unroll
    for (int ii = 0; ii < 2; ii++)
        pre[ii] = *(const short8*)&W2f[8192 + ii * 4096 + t * 8];
    __syncthreads();   // B2 chunk0 ready

    float tps[2][4];     // [et][r]: out_s[e=eb+et*16+m][j=(cg&1)*16+q*4+r], half=(cg>>1)
    float tpv[2][4][3];  // [et][r][mm]: out_v[e][jv=(q&1)*4+r][mm], slot=cg, parity=(q>>1)
    #pragma unroll
    for (int et = 0; et < 2; et++)
        #pragma unroll
        for (int r = 0; r < 4; r++) {
            tps[et][r] = 0.f;
            tpv[et][r][0] = 0.f; tpv[et][r][1] = 0.f; tpv[et][r][2] = 0.f;
        }

    for (int c = 0; c < 25; c++) {
        floatx4 bias = *(const floatx4*)&b2s[c * 64 + cg * 16 + q * 4];
        floatx4 acc[2];
        acc[0] = bias; acc[1] = bias;
        #pragma unroll
        for (int kk = 0; kk < 4; kk++) {
            short8 a = *(const short8*)&B2[(kk * 4 + cg) * 512 + lane * 8];  // lane-contiguous
            acc[0] = __builtin_amdgcn_mfma_f32_16x16x32_bf16(a, hc[0][kk], acc[0], 0, 0, 0);
            acc[1] = __builtin_amdgcn_mfma_f32_16x16x32_bf16(a, hc[1][kk], acc[1], 0, 0, 0);
        }

        // consume from registers (lane holds w[gcol=c*64+cg*16+q*4+r][e=eb+et*16+m])
        if (c < 16) {                       // ss: i = 2c + (cg>>1)
            const int i = 2 * c + (cg >> 1);
            #pragma unroll
            for (int et = 0; et < 2; et++) {
                float f = bf2f(sF[i * 64 + eb + et * 16 + m]) * ssc[et];
                #pragma unroll
                for (int r = 0; r < 4; r++) tps[et][r] += acc[et][r] * f;
            }
        } else if (c < 20) {                // vs: i = 2(c-16) + (cg>>1), f = dot
            const int i = 2 * (c - 16) + (cg >> 1);
            #pragma unroll
            for (int et = 0; et < 2; et++) {
                float f = bf2f(sF[(32 + i) * 64 + eb + et * 16 + m]);
                #pragma unroll
                for (int r = 0; r < 4; r++) tps[et][r] += acc[et][r] * f;
            }
        } else if (c < 24) {                // sv: i = 8(c-20) + cg*2 + (q>>1), f = xs
            const int i = 8 * (c - 20) + cg * 2 + (q >> 1);
            #pragma unroll
            for (int et = 0; et < 2; et++) {
                float f = bf2f(sF[i * 64 + eb + et * 16 + m]);
                #pragma unroll
                for (int r = 0; r < 4; r++) {
                    float t0 = acc[et][r] * f;
                    tpv[et][r][0] += t0 * svc[et][0];
                    tpv[et][r][1] += t0 * svc[et][1];
                    tpv[et][r][2] += t0 * svc[et][2];
                }
            }
        } else {                            // vv: i = cg*2 + (q>>1), f = xv*ss
            const int i = cg * 2 + (q >> 1);
            #pragma unroll
            for (int et = 0; et < 2; et++) {
                float x0 = bf2f(sF[(40 + 3 * i + 0) * 64 + eb + et * 16 + m]) * ssc[et];
                float x1 = bf2f(sF[(40 + 3 * i + 1) * 64 + eb + et * 16 + m]) * ssc[et];
                float x2 = bf2f(sF[(40 + 3 * i + 2) * 64 + eb + et * 16 + m]) * ssc[et];
                #pragma unroll
                for (int r = 0; r < 4; r++) {
                    tpv[et][r][0] += acc[et][r] * x0;
                    tpv[et][r][1] += acc[et][r] * x1;
                    tpv[et][r][2] += acc[et][r] * x2;
                }
            }
        }

        __syncthreads();   // B2 A-frag reads done
        if (c < 24) {
            #pragma unroll
            for (int ii = 0; ii < 2; ii++)
                *(short8*)&B2[ii * 4096 + t * 8] = pre[ii];
            if (c < 23) {
                #pragma unroll
                for (int ii = 0; ii < 2; ii++)
                    pre[ii] = *(const short8*)&W2f[(size_t)(c + 2) * 8192 + ii * 4096 + t * 8];
            }
        }
        __syncthreads();   // next B2 ready
    }

    // ---- end-stage combine (overlay smem) ----
    #pragma unroll
    for (int et = 0; et < 2; et++)
        #pragma unroll
        for (int r = 0; r < 4; r++)
            Ssc[(cg >> 1) * 2112 + (eb + et * 16 + m) * 33 + (cg & 1) * 16 + q * 4 + r] = tps[et][r];
    #pragma unroll
    for (int et = 0; et < 2; et++)
        #pragma unroll
        for (int r = 0; r < 4; r++)
            #pragma unroll
            for (int mm = 0; mm < 3; mm++) {
                float v = tpv[et][r][mm];
                v += __shfl_xor(v, 32, 64);
                if (q < 2)
                    Svec[cg * 1600 + (eb + et * 16 + m) * 25 + ((q & 1) * 4 + r) * 3 + mm] = v;
            }
    __syncthreads();

    for (int idx = t; idx < 3584; idx += 512) {
        int e = idx / 56, d = idx - e * 56;
        float v;
        if (d < 32) {
            v = Ssc[e * 33 + d] + Ssc[2112 + e * 33 + d];
        } else {
            int dd = d - 32;
            v = Svec[e * 25 + dd] + Svec[1600 + e * 25 + dd]
              + Svec[3200 + e * 25 + dd] + Svec[4800 + e * 25 + dd];
        }
        tp[(size_t)(p0 + e) * DD + d] = v * PATH_NORMF;   // CSR position order
    }
}

// ---------------- K3: contiguous segment-mean + residual + BN stat atomics ----------------
__global__ __launch_bounds__(256) void gather_finalize(
    const float* __restrict__ tp, const int* __restrict__ row_start,
    const float* __restrict__ node_attr,
    float* __restrict__ ybuf, float* __restrict__ stats)
{
    __shared__ float ps[4][72];
    const int wv = threadIdx.x >> 6, lane = threadIdx.x & 63;
    const int n = blockIdx.x * 4 + wv;    // 4096 blocks
    const int beg = row_start[n], end = row_start[n + 1];
    if (lane < 56) {
        float acc = 0.f;
        for (int p = beg; p < end; p++)
            acc += tp[(size_t)p * DD + lane];   // fully coalesced, sequential
        float inv = 1.f / fmaxf((float)(end - beg), 1.f);
        float y = acc * inv + node_attr[(size_t)n * DD + lane];
        ybuf[(size_t)n * DD + lane] = y;
        if (lane < 32) {
            ps[wv][lane] = y;
            ps[wv][32 + lane] = y * y;
        } else {
            float vv = y * y;
            float v1 = __shfl_down(vv, 1, 64);
            float v2 = __shfl_down(vv, 2, 64);
            int l3 = lane - 32;
            if (l3 % 3 == 0) ps[wv][64 + l3 / 3] = vv + v1 + v2;
        }
    }
    __syncthreads();
    const int t = threadIdx.x;
    if (t < 72)
        atomicAdd(&stats[t], ps[0][t] + ps[1][t] + ps[2][t] + ps[3][t]);
}

// ---------------- K4: batch-norm apply + write fp32 output ----------------
__global__ __launch_bounds__(256) void bn_apply(
    const float* __restrict__ ybuf, const float* __restrict__ stats,
    const float* __restrict__ gamma, const float* __restrict__ beta,
    float* __restrict__ out)
{
    const int i = blockIdx.x * 256 + threadIdx.x;   // 3584*256 = 917504
    const int n = i / 56;
    const int d = i - n * 56;
    const float invN = 1.f / 16384.f;
    float y = ybuf[i];
    float o;
    if (d < 32) {
        float mn  = stats[d] * invN;
        float var = stats[32 + d] * invN - mn * mn;
        o = (y - mn) * rsqrtf(var + 1e-5f) * gamma[d] + beta[d];
    } else {
        int jv = (d - 32) / 3;
        o = y * rsqrtf(stats[64 + jv] * invN + 1e-5f) * gamma[32 + jv];
    }
    out[i] = o;
}

// ---------------- launch ----------------
extern "C" void kernel_launch(void* const* d_in, const int* in_sizes, int n_in,
                              void* d_out, int out_size, void* d_ws, size_t ws_size,
                              hipStream_t stream)
{
    const float* node_attr = (const float*)d_in[0];
    const float* edge_attr = (const float*)d_in[1];
    const float* edge_sh   = (const float*)d_in[2];
    const float* W1        = (const float*)d_in[3];
    const float* b1        = (const float*)d_in[4];
    const float* W2        = (const float*)d_in[5];
    const float* b2        = (const float*)d_in[6];
    const float* gamma     = (const float*)d_in[7];
    const float* beta      = (const float*)d_in[8];
    const int*   eidx      = (const int*)d_in[9];

    char* ws = (char*)d_ws;
    u16*   W1f        = (u16*)(ws);                  // 32768 B
    u16*   W2f        = (u16*)(ws + 32768);          // 409600   -> 442368
    int*   deg        = (int*)(ws + 442368);         // 65536    -> 507904
    float* stats      = (float*)(ws + 507904);       // 512      -> 508416   (memset w/ deg)
    int*   row_start  = (int*)(ws + 508416);         // 65792    -> 574208
    int*   cursor     = (int*)(ws + 574208);         // 65536    -> 639744
    int*   edge_order = (int*)(ws + 639744);         // 524288   -> 1164032
    float* tp         = (float*)(ws + 1164032);      // 29360128 -> 30524160
    float* ybuf       = (float*)(ws + 30524160);     // 3670016  -> 34194176 (~34.2 MB)

    (void)hipMemsetAsync(deg, 0, 66048, stream);     // deg + stats
    hipLaunchKernelGGL(prep,            dim3(1376), dim3(256),  0, stream,
                       W1, W2, W1f, W2f, eidx, deg);
    hipLaunchKernelGGL(deg_scan,        dim3(1),    dim3(1024), 0, stream, deg, row_start, cursor);
    hipLaunchKernelGGL(edge_scatter,    dim3(512),  dim3(256),  0, stream, eidx, cursor, edge_order);
    hipLaunchKernelGGL(tpconv,          dim3(2048), dim3(512),  0, stream,
                       node_attr, edge_attr, edge_sh, W1f, b1, W2f, b2, eidx, edge_order, tp);
    hipLaunchKernelGGL(gather_finalize, dim3(4096), dim3(256),  0, stream,
                       tp, row_start, node_attr, ybuf, stats);
    hipLaunchKernelGGL(bn_apply,        dim3(3584), dim3(256),  0, stream,
                       ybuf, stats, gamma, beta, (float*)d_out);
}

// Round 13
// 248.786 us; speedup vs baseline: 1.9755x; 1.3439x over previous
//
#include <hip/hip_runtime.h>

typedef short short8 __attribute__((ext_vector_type(8)));
typedef unsigned short us4 __attribute__((ext_vector_type(4)));
typedef float floatx4 __attribute__((ext_vector_type(4)));
typedef unsigned short u16;

#define NN 16384
#define NE 131072
#define NEF_ 128
#define DD 56
#define INV_SQRT3F 0.57735026918962576f
#define PATH_NORMF 0.15811388300841897f

__device__ __forceinline__ float bf2f(u16 u) {
    union { unsigned int i; float f; } v; v.i = ((unsigned int)u) << 16; return v.f;
}
__device__ __forceinline__ u16 f2bf(float f) {
    union { float f; unsigned int i; } v; v.f = f;
    unsigned int r = v.i + 0x7fffu + ((v.i >> 16) & 1u);
    return (u16)(r >> 16);
}

// ---------------- K0: build FRAG-MAJOR W1f/W2f + edge-src histogram ----------------
__global__ __launch_bounds__(256) void prep(const float* __restrict__ W1,
                                            const float* __restrict__ W2,
                                            u16* __restrict__ W1f,
                                            u16* __restrict__ W2f,
                                            const int* __restrict__ eidx,
                                            int* __restrict__ deg) {
    int b = blockIdx.x;
    if (b < 864) {
        int i = b * 256 + threadIdx.x;   // 221184 = 16384 + 204800
        if (i < 16384) {
            int cc = i >> 13, kk = (i >> 11) & 3, cg = (i >> 9) & 3;
            int lane = (i >> 3) & 63, j = i & 7;
            int q = lane >> 4, m = lane & 15;
            W1f[i] = f2bf(W1[(kk * 32 + q * 8 + j) * 128 + cc * 64 + cg * 16 + m]);
        } else {
            int f = i - 16384;
            int c = f >> 13, kk = (f >> 11) & 3, cg = (f >> 9) & 3;
            int lane = (f >> 3) & 63, j = f & 7;
            int q = lane >> 4, m = lane & 15;
            W2f[f] = f2bf(W2[(kk * 32 + q * 8 + j) * 1600 + c * 64 + cg * 16 + m]);
        }
    } else {
        int e = (b - 864) * 256 + threadIdx.x;
        atomicAdd(&deg[eidx[e]], 1);
    }
}

__global__ __launch_bounds__(1024) void deg_scan(const int* __restrict__ deg,
                                                 int* __restrict__ row_start,
                                                 int* __restrict__ cursor) {
    __shared__ int part[1024];
    const int t = threadIdx.x;
    const int base = t * 16;
    int loc[16];
    int s = 0;
    #pragma unroll
    for (int i = 0; i < 16; i++) { loc[i] = s; s += deg[base + i]; }
    part[t] = s;
    __syncthreads();
    for (int off = 1; off < 1024; off <<= 1) {
        int v = (t >= off) ? part[t - off] : 0;
        __syncthreads();
        part[t] += v;
        __syncthreads();
    }
    int pre = (t == 0) ? 0 : part[t - 1];
    #pragma unroll
    for (int i = 0; i < 16; i++) {
        int v = pre + loc[i];
        row_start[base + i] = v;
        cursor[base + i] = v;
    }
    if (t == 1023) row_start[16384] = pre + s;
}

__global__ __launch_bounds__(256) void edge_scatter(const int* __restrict__ eidx,
                                                    int* __restrict__ cursor,
                                                    int* __restrict__ edge_order) {
    int e = blockIdx.x * 256 + threadIdx.x;
    int p = atomicAdd(&cursor[eidx[e]], 1);
    edge_order[p] = e;
}

// ---------------- K2: fused MLP + tensor product, 512 threads, double-buffered B2 ----------------
// 8 waves: cg = wv&3 (16 w-cols), eh = wv>>2 (32 edges, 2 et-tiles).
// After hc is register-cached, sA is dead -> B2's second buffer OVERLAYS sA (no extra LDS).
// One barrier per chunk.
__global__ __launch_bounds__(512, 4) void tpconv(
    const float* __restrict__ node_attr, const float* __restrict__ edge_attr,
    const float* __restrict__ edge_sh, const u16* __restrict__ W1f,
    const float* __restrict__ b1, const u16* __restrict__ W2f,
    const float* __restrict__ b2, const int* __restrict__ eidx,
    const int* __restrict__ edge_order,
    float* __restrict__ tp)
{
    __shared__ __align__(16) char smem[48896];
    u16*   sA  = (u16*)smem;                 // 64*136 u16 = 17408 B (edge_attr, then h; dead after hc)
    u16*   B2a = (u16*)(smem + 17408);       // 16384 B frag-major chunk (even parity) -> 33792
    u16*   B2b = (u16*)smem;                 // 16384 B (odd parity) — overlays sA
    u16*   sF  = (u16*)(smem + 33792);       // 68*64 u16 = 8704 B -> 42496
    float* b2s = (float*)(smem + 42496);     // 1600 f32 = 6400 B -> 48896
    float* Ssc  = (float*)smem;              // overlay: 2 * 64*33 f32 = 16896 B
    float* Svec = (float*)(smem + 16896);    // overlay: 4 * 64*25 f32 -> 42496 (b2s untouched)

    const int t = threadIdx.x;
    const int lane = t & 63;
    const int wv = t >> 6;           // 0..7
    const int m = lane & 15;
    const int q = lane >> 4;
    const int cg = wv & 3;           // col-group (16 w-cols)
    const int eh = wv >> 2;          // edge-half
    const int eb = eh * 32;          // edge base
    const int p0 = blockIdx.x * 64;  // CSR position base

    // early prefetch of W2f chunk 0 (contiguous: 2 x 16B per thread)
    short8 pre[2];
    #pragma unroll
    for (int ii = 0; ii < 2; ii++)
        pre[ii] = *(const short8*)&W2f[ii * 4096 + t * 8];

    for (int i = t; i < 1600; i += 512) b2s[i] = b2[i];

    // stage edge_attr tile (64 gathered rows, fp32 -> bf16)
    #pragma unroll
    for (int ii = 0; ii < 4; ii++) {
        int cid = t + 512 * ii;
        int r = cid >> 5, s = cid & 31;
        int e = edge_order[p0 + r];
        const float* src = &edge_attr[(size_t)e * NEF_ + s * 4];
        us4 o;
        o.x = f2bf(src[0]); o.y = f2bf(src[1]); o.z = f2bf(src[2]); o.w = f2bf(src[3]);
        *(us4*)&sA[r * 136 + s * 4] = o;
    }
    // per-edge factors (wave 0)
    if (t < 64) {
        int e = edge_order[p0 + t];
        int nd = eidx[NE + e];
        const float* na = node_attr + (size_t)nd * DD;
        const float* sh = edge_sh + (size_t)e * 4;
        float ss = sh[0], s0 = sh[1], s1 = sh[2], s2 = sh[3];
        #pragma unroll
        for (int i = 0; i < 32; i++) sF[i * 64 + t] = f2bf(na[i]);
        #pragma unroll
        for (int i = 0; i < 8; i++) {
            float d = (na[32+i*3]*s0 + na[33+i*3]*s1 + na[34+i*3]*s2) * INV_SQRT3F;
            sF[(32 + i) * 64 + t] = f2bf(d);
        }
        #pragma unroll
        for (int i = 0; i < 24; i++) sF[(40 + i) * 64 + t] = f2bf(na[32 + i]);
        sF[64 * 64 + t] = f2bf(ss);
        sF[65 * 64 + t] = f2bf(s0);
        sF[66 * 64 + t] = f2bf(s1);
        sF[67 * 64 + t] = f2bf(s2);
    }
    __syncthreads();

    // ---- h = relu(ea @ W1 + b1), two 64-col passes; W1f staged frag-major in B2a ----
    floatx4 hacc[2][2];
    #pragma unroll
    for (int cc = 0; cc < 2; cc++) {
        #pragma unroll
        for (int ii = 0; ii < 2; ii++)
            *(short8*)&B2a[ii * 4096 + t * 8] =
                *(const short8*)&W1f[cc * 8192 + ii * 4096 + t * 8];
        __syncthreads();
        {
            float bv = b1[cc * 64 + cg * 16 + m];
            hacc[cc][0] = (floatx4){bv, bv, bv, bv};
            hacc[cc][1] = hacc[cc][0];
        }
        #pragma unroll
        for (int kk = 0; kk < 4; kk++) {
            short8 a0 = *(const short8*)&sA[(eb      + m) * 136 + kk * 32 + q * 8];
            short8 a1 = *(const short8*)&sA[(eb + 16 + m) * 136 + kk * 32 + q * 8];
            short8 bA = *(const short8*)&B2a[(kk * 4 + cg) * 512 + lane * 8];
            hacc[cc][0] = __builtin_amdgcn_mfma_f32_16x16x32_bf16(a0, bA, hacc[cc][0], 0, 0, 0);
            hacc[cc][1] = __builtin_amdgcn_mfma_f32_16x16x32_bf16(a1, bA, hacc[cc][1], 0, 0, 0);
        }
        __syncthreads();
    }
    // write h (relu, bf16): row(edge) = eb + rt*16 + q*4+r, col = cc*64 + cg*16 + m
    #pragma unroll
    for (int cc = 0; cc < 2; cc++)
      #pragma unroll
      for (int rt = 0; rt < 2; rt++)
        #pragma unroll
        for (int r = 0; r < 4; r++) {
            int e   = eb + rt * 16 + q * 4 + r;
            int col = cc * 64 + cg * 16 + m;
            float v = hacc[cc][rt][r];
            sA[e * 136 + col] = f2bf(v > 0.f ? v : 0.f);
        }
    __syncthreads();   // h complete

    // h-cache: B-fragments for this wave's 2 edge-tiles (32 VGPR, reused 25x)
    short8 hc[2][4];
    #pragma unroll
    for (int et = 0; et < 2; et++)
        #pragma unroll
        for (int kk = 0; kk < 4; kk++)
            hc[et][kk] = *(const short8*)&sA[(eb + et * 16 + m) * 136 + kk * 32 + q * 8];

    float ssc[2], svc[2][3];
    #pragma unroll
    for (int et = 0; et < 2; et++) {
        ssc[et] = bf2f(sF[64 * 64 + eb + et * 16 + m]);
        svc[et][0] = bf2f(sF[65 * 64 + eb + et * 16 + m]);
        svc[et][1] = bf2f(sF[66 * 64 + eb + et * 16 + m]);
        svc[et][2] = bf2f(sF[67 * 64 + eb + et * 16 + m]);
    }

    // commit W2f chunk 0 -> B2a; prefetch chunk 1
    #pragma unroll
    for (int ii = 0; ii < 2; ii++)
        *(short8*)&B2a[ii * 4096 + t * 8] = pre[ii];
    #pragma unroll
    for (int ii = 0; ii < 2; ii++)
        pre[ii] = *(const short8*)&W2f[8192 + ii * 4096 + t * 8];
    __syncthreads();   // B2a chunk0 ready; sA reads (hc/ssc) fully drained -> B2b writable

    float tps[2][4];     // [et][r]: out_s[e=eb+et*16+m][j=(cg&1)*16+q*4+r], half=(cg>>1)
    float tpv[2][4][3];  // [et][r][mm]: out_v[e][jv=(q&1)*4+r][mm], slot=cg, parity=(q>>1)
    #pragma unroll
    for (int et = 0; et < 2; et++)
        #pragma unroll
        for (int r = 0; r < 4; r++) {
            tps[et][r] = 0.f;
            tpv[et][r][0] = 0.f; tpv[et][r][1] = 0.f; tpv[et][r][2] = 0.f;
        }

    // ---- 25 chunks, double-buffered B2, ONE barrier per chunk ----
    for (int c = 0; c < 25; c++) {
        const u16* rb = (c & 1) ? B2b : B2a;   // read buffer (chunk c)
        u16*       wb = (c & 1) ? B2a : B2b;   // write buffer (chunk c+1)

        floatx4 bias = *(const floatx4*)&b2s[c * 64 + cg * 16 + q * 4];
        floatx4 acc[2];
        acc[0] = bias; acc[1] = bias;
        #pragma unroll
        for (int kk = 0; kk < 4; kk++) {
            short8 a = *(const short8*)&rb[(kk * 4 + cg) * 512 + lane * 8];  // lane-contiguous
            acc[0] = __builtin_amdgcn_mfma_f32_16x16x32_bf16(a, hc[0][kk], acc[0], 0, 0, 0);
            acc[1] = __builtin_amdgcn_mfma_f32_16x16x32_bf16(a, hc[1][kk], acc[1], 0, 0, 0);
        }

        // stage chunk c+1 into the other buffer (its readers finished before prev barrier)
        if (c < 24) {
            #pragma unroll
            for (int ii = 0; ii < 2; ii++)
                *(short8*)&wb[ii * 4096 + t * 8] = pre[ii];
            if (c < 23) {
                #pragma unroll
                for (int ii = 0; ii < 2; ii++)
                    pre[ii] = *(const short8*)&W2f[(size_t)(c + 2) * 8192 + ii * 4096 + t * 8];
            }
        }

        // consume from registers (lane holds w[gcol=c*64+cg*16+q*4+r][e=eb+et*16+m])
        if (c < 16) {                       // ss: i = 2c + (cg>>1)
            const int i = 2 * c + (cg >> 1);
            #pragma unroll
            for (int et = 0; et < 2; et++) {
                float f = bf2f(sF[i * 64 + eb + et * 16 + m]) * ssc[et];
                #pragma unroll
                for (int r = 0; r < 4; r++) tps[et][r] += acc[et][r] * f;
            }
        } else if (c < 20) {                // vs: i = 2(c-16) + (cg>>1), f = dot
            const int i = 2 * (c - 16) + (cg >> 1);
            #pragma unroll
            for (int et = 0; et < 2; et++) {
                float f = bf2f(sF[(32 + i) * 64 + eb + et * 16 + m]);
                #pragma unroll
                for (int r = 0; r < 4; r++) tps[et][r] += acc[et][r] * f;
            }
        } else if (c < 24) {                // sv: i = 8(c-20) + cg*2 + (q>>1), f = xs
            const int i = 8 * (c - 20) + cg * 2 + (q >> 1);
            #pragma unroll
            for (int et = 0; et < 2; et++) {
                float f = bf2f(sF[i * 64 + eb + et * 16 + m]);
                #pragma unroll
                for (int r = 0; r < 4; r++) {
                    float t0 = acc[et][r] * f;
                    tpv[et][r][0] += t0 * svc[et][0];
                    tpv[et][r][1] += t0 * svc[et][1];
                    tpv[et][r][2] += t0 * svc[et][2];
                }
            }
        } else {                            // vv: i = cg*2 + (q>>1), f = xv*ss
            const int i = cg * 2 + (q >> 1);
            #pragma unroll
            for (int et = 0; et < 2; et++) {
                float x0 = bf2f(sF[(40 + 3 * i + 0) * 64 + eb + et * 16 + m]) * ssc[et];
                float x1 = bf2f(sF[(40 + 3 * i + 1) * 64 + eb + et * 16 + m]) * ssc[et];
                float x2 = bf2f(sF[(40 + 3 * i + 2) * 64 + eb + et * 16 + m]) * ssc[et];
                #pragma unroll
                for (int r = 0; r < 4; r++) {
                    tpv[et][r][0] += acc[et][r] * x0;
                    tpv[et][r][1] += acc[et][r] * x1;
                    tpv[et][r][2] += acc[et][r] * x2;
                }
            }
        }

        __syncthreads();   // chunk c reads + chunk c+1 writes complete
    }

    // ---- end-stage combine (overlay smem; final loop barrier drained everything) ----
    #pragma unroll
    for (int et = 0; et < 2; et++)
        #pragma unroll
        for (int r = 0; r < 4; r++)
            Ssc[(cg >> 1) * 2112 + (eb + et * 16 + m) * 33 + (cg & 1) * 16 + q * 4 + r] = tps[et][r];
    #pragma unroll
    for (int et = 0; et < 2; et++)
        #pragma unroll
        for (int r = 0; r < 4; r++)
            #pragma unroll
            for (int mm = 0; mm < 3; mm++) {
                float v = tpv[et][r][mm];
                v += __shfl_xor(v, 32, 64);
                if (q < 2)
                    Svec[cg * 1600 + (eb + et * 16 + m) * 25 + ((q & 1) * 4 + r) * 3 + mm] = v;
            }
    __syncthreads();

    for (int idx = t; idx < 3584; idx += 512) {
        int e = idx / 56, d = idx - e * 56;
        float v;
        if (d < 32) {
            v = Ssc[e * 33 + d] + Ssc[2112 + e * 33 + d];
        } else {
            int dd = d - 32;
            v = Svec[e * 25 + dd] + Svec[1600 + e * 25 + dd]
              + Svec[3200 + e * 25 + dd] + Svec[4800 + e * 25 + dd];
        }
        tp[(size_t)(p0 + e) * DD + d] = v * PATH_NORMF;   // CSR position order
    }
}

// ---------------- K3: contiguous segment-mean + residual + per-block BN partials ----------------
__global__ __launch_bounds__(256) void gather_finalize(
    const float* __restrict__ tp, const int* __restrict__ row_start,
    const float* __restrict__ node_attr,
    float* __restrict__ ybuf, float* __restrict__ partial)
{
    __shared__ float ps[4][72];
    const int wv = threadIdx.x >> 6, lane = threadIdx.x & 63;
    const int n = blockIdx.x * 4 + wv;    // 4096 blocks
    const int beg = row_start[n], end = row_start[n + 1];
    if (lane < 56) {
        float acc = 0.f;
        for (int p = beg; p < end; p++)
            acc += tp[(size_t)p * DD + lane];   // fully coalesced, sequential
        float inv = 1.f / fmaxf((float)(end - beg), 1.f);
        float y = acc * inv + node_attr[(size_t)n * DD + lane];
        ybuf[(size_t)n * DD + lane] = y;
        if (lane < 32) {
            ps[wv][lane] = y;
            ps[wv][32 + lane] = y * y;
        } else {
            float vv = y * y;
            float v1 = __shfl_down(vv, 1, 64);
            float v2 = __shfl_down(vv, 2, 64);
            int l3 = lane - 32;
            if (l3 % 3 == 0) ps[wv][64 + l3 / 3] = vv + v1 + v2;
        }
    }
    __syncthreads();
    const int t = threadIdx.x;
    if (t < 72)
        partial[(size_t)blockIdx.x * 72 + t] = ps[0][t] + ps[1][t] + ps[2][t] + ps[3][t];
}

// ---------------- K4: reduce BN partials (no atomic contention) ----------------
__global__ __launch_bounds__(256) void bn_reduce(const float* __restrict__ partial,
                                                 float* __restrict__ stats)
{
    __shared__ float red[256];
    const int d = blockIdx.x;   // 0..71
    const int t = threadIdx.x;
    float a = 0.f;
    for (int i = t; i < 4096; i += 256) a += partial[(size_t)i * 72 + d];
    red[t] = a;
    __syncthreads();
    for (int off = 128; off > 0; off >>= 1) {
        if (t < off) red[t] += red[t + off];
        __syncthreads();
    }
    if (t == 0) stats[d] = red[0] * (1.f / 16384.f);
}

// ---------------- K5: batch-norm apply + write fp32 output ----------------
__global__ __launch_bounds__(256) void bn_apply(
    const float* __restrict__ ybuf, const float* __restrict__ stats,
    const float* __restrict__ gamma, const float* __restrict__ beta,
    float* __restrict__ out)
{
    const int i = blockIdx.x * 256 + threadIdx.x;   // 3584*256 = 917504
    const int n = i / 56;
    const int d = i - n * 56;
    float y = ybuf[i];
    float o;
    if (d < 32) {
        float mn  = stats[d];
        float var = stats[32 + d] - mn * mn;
        o = (y - mn) * rsqrtf(var + 1e-5f) * gamma[d] + beta[d];
    } else {
        int jv = (d - 32) / 3;
        o = y * rsqrtf(stats[64 + jv] + 1e-5f) * gamma[32 + jv];
    }
    out[i] = o;
}

// ---------------- launch ----------------
extern "C" void kernel_launch(void* const* d_in, const int* in_sizes, int n_in,
                              void* d_out, int out_size, void* d_ws, size_t ws_size,
                              hipStream_t stream)
{
    const float* node_attr = (const float*)d_in[0];
    const float* edge_attr = (const float*)d_in[1];
    const float* edge_sh   = (const float*)d_in[2];
    const float* W1        = (const float*)d_in[3];
    const float* b1        = (const float*)d_in[4];
    const float* W2        = (const float*)d_in[5];
    const float* b2        = (const float*)d_in[6];
    const float* gamma     = (const float*)d_in[7];
    const float* beta      = (const float*)d_in[8];
    const int*   eidx      = (const int*)d_in[9];

    char* ws = (char*)d_ws;
    u16*   W1f        = (u16*)(ws);                  // 32768 B
    u16*   W2f        = (u16*)(ws + 32768);          // 409600   -> 442368
    int*   deg        = (int*)(ws + 442368);         // 65536    -> 507904
    int*   row_start  = (int*)(ws + 507904);         // 65792    -> 573696
    int*   cursor     = (int*)(ws + 573696);         // 65536    -> 639232
    int*   edge_order = (int*)(ws + 639232);         // 524288   -> 1163520
    float* stats      = (float*)(ws + 1163520);      // 512      -> 1164032
    float* partial    = (float*)(ws + 1164032);      // 1179648  -> 2343680
    float* tp         = (float*)(ws + 2343680);      // 29360128 -> 31703808
    float* ybuf       = (float*)(ws + 31703808);     // 3670016  -> 35373824 (~35.4 MB)

    (void)hipMemsetAsync(deg, 0, 65536, stream);
    hipLaunchKernelGGL(prep,            dim3(1376), dim3(256),  0, stream,
                       W1, W2, W1f, W2f, eidx, deg);
    hipLaunchKernelGGL(deg_scan,        dim3(1),    dim3(1024), 0, stream, deg, row_start, cursor);
    hipLaunchKernelGGL(edge_scatter,    dim3(512),  dim3(256),  0, stream, eidx, cursor, edge_order);
    hipLaunchKernelGGL(tpconv,          dim3(2048), dim3(512),  0, stream,
                       node_attr, edge_attr, edge_sh, W1f, b1, W2f, b2, eidx, edge_order, tp);
    hipLaunchKernelGGL(gather_finalize, dim3(4096), dim3(256),  0, stream,
                       tp, row_start, node_attr, ybuf, partial);
    hipLaunchKernelGGL(bn_reduce,       dim3(72),   dim3(256),  0, stream, partial, stats);
    hipLaunchKernelGGL(bn_apply,        dim3(3584), dim3(256),  0, stream,
                       ybuf, stats, gamma, beta, (float*)d_out);
}